// Round 1
// baseline (4088.880 us; speedup 1.0000x reference)
//
#include <hip/hip_runtime.h>
#include <math.h>

#define B_  4
#define S_  2048
#define D_  1024
#define H_  16
#define DH_ 64
#define M_  (B_*S_)

// ---------------------------------------------------------------------------
// GEMM: Y = X @ W^T + bias.  X:[M,K] row-major, W:[N,K] row-major (torch
// Linear weight).  mode 0: write Y[m*N+n].  mode 1: scatter to [B,H,S,dh].
// 64x64 tile, TK=16, 256 threads, 4x4 micro-tile per thread.
// ---------------------------------------------------------------------------
__global__ __launch_bounds__(256)
void gemm_xwt(const float* __restrict__ X, const float* __restrict__ W,
              const float* __restrict__ bias, float* __restrict__ Y,
              int M, int N, int K, int mode)
{
    __shared__ float As[64][17];
    __shared__ float Bs[64][17];
    const int t  = threadIdx.x;
    const int tx = t & 15, ty = t >> 4;
    const int m0 = blockIdx.x * 64, n0 = blockIdx.y * 64;
    const int lr = t >> 2;          // 0..63 row to load
    const int lc = (t & 3) * 4;     // 0,4,8,12 col-start to load

    float acc[4][4];
    #pragma unroll
    for (int i = 0; i < 4; i++)
        #pragma unroll
        for (int j = 0; j < 4; j++) acc[i][j] = 0.f;

    for (int k0 = 0; k0 < K; k0 += 16) {
        float4 a = *(const float4*)&X[(size_t)(m0 + lr) * K + k0 + lc];
        float4 b = *(const float4*)&W[(size_t)(n0 + lr) * K + k0 + lc];
        __syncthreads();   // previous iteration's LDS reads complete
        As[lr][lc+0] = a.x; As[lr][lc+1] = a.y; As[lr][lc+2] = a.z; As[lr][lc+3] = a.w;
        Bs[lr][lc+0] = b.x; Bs[lr][lc+1] = b.y; Bs[lr][lc+2] = b.z; Bs[lr][lc+3] = b.w;
        __syncthreads();
        #pragma unroll
        for (int kk = 0; kk < 16; kk++) {
            float av[4], bv[4];
            #pragma unroll
            for (int i = 0; i < 4; i++) av[i] = As[ty*4 + i][kk];
            #pragma unroll
            for (int j = 0; j < 4; j++) bv[j] = Bs[tx*4 + j][kk];
            #pragma unroll
            for (int i = 0; i < 4; i++)
                #pragma unroll
                for (int j = 0; j < 4; j++) acc[i][j] += av[i] * bv[j];
        }
    }

    const int nbase = n0 + tx*4;
    float4 bi = *(const float4*)&bias[nbase];
    #pragma unroll
    for (int i = 0; i < 4; i++) {
        const int m = m0 + ty*4 + i;
        float4 r;
        r.x = acc[i][0] + bi.x;
        r.y = acc[i][1] + bi.y;
        r.z = acc[i][2] + bi.z;
        r.w = acc[i][3] + bi.w;
        if (mode == 0) {
            *(float4*)&Y[(size_t)m * N + nbase] = r;
        } else {
            const int b = m >> 11, s = m & (S_ - 1);
            const int head = nbase >> 6, d = nbase & (DH_ - 1);
            const size_t idx = (((size_t)b * H_ + head) * S_ + s) * DH_ + d;
            *(float4*)&Y[idx] = r;
        }
    }
}

// ---------------------------------------------------------------------------
// Flash-style causal attention.  Q/K/V: [B,H,S,dh] fp32.  out: [B,S,D].
// One block (256 thr) per (qtile of 64, b*H+h).  Thread t owns row r=t/4,
// cols c0=(t%4)*16 .. +15 of both the 64x64 score tile and the O accumulator.
// ---------------------------------------------------------------------------
__global__ __launch_bounds__(256)
void attn_kernel(const float* __restrict__ q, const float* __restrict__ k,
                 const float* __restrict__ v, float* __restrict__ out)
{
    __shared__ float Qs[64][68];
    __shared__ float Ks[64][68];
    __shared__ float Vs[64][68];
    __shared__ float Ps[64][65];
    __shared__ float m_s[64], l_s[64], a_s[64];
    __shared__ float red[64][4];

    const int t     = threadIdx.x;
    const int qtile = blockIdx.x;          // 0..31
    const int bh    = blockIdx.y;          // 0..63
    const int q0    = qtile * 64;
    const int r     = t >> 2;
    const int c0    = (t & 3) * 16;

    const float* qbase = q + ((size_t)bh * S_ + q0) * DH_;

    // load Q tile (4096 floats, 4 x float4 per thread)
    #pragma unroll
    for (int i = 0; i < 4; i++) {
        const int f  = t + i * 256;
        const int rr = f >> 4, cc = (f & 15) * 4;
        float4 val = *(const float4*)&qbase[(size_t)rr * DH_ + cc];
        Qs[rr][cc+0] = val.x; Qs[rr][cc+1] = val.y; Qs[rr][cc+2] = val.z; Qs[rr][cc+3] = val.w;
    }
    float o[16];
    #pragma unroll
    for (int i = 0; i < 16; i++) o[i] = 0.f;
    if (t < 64) { m_s[t] = -INFINITY; l_s[t] = 0.f; }
    __syncthreads();

    const int ktiles = qtile + 1;
    for (int kt = 0; kt < ktiles; kt++) {
        const int k0 = kt * 64;
        const float* kbase = k + ((size_t)bh * S_ + k0) * DH_;
        const float* vbase = v + ((size_t)bh * S_ + k0) * DH_;
        float4 kv[4], vv[4];
        #pragma unroll
        for (int i = 0; i < 4; i++) {
            const int f  = t + i * 256;
            const int rr = f >> 4, cc = (f & 15) * 4;
            kv[i] = *(const float4*)&kbase[(size_t)rr * DH_ + cc];
            vv[i] = *(const float4*)&vbase[(size_t)rr * DH_ + cc];
        }
        __syncthreads();   // previous tile fully consumed
        #pragma unroll
        for (int i = 0; i < 4; i++) {
            const int f  = t + i * 256;
            const int rr = f >> 4, cc = (f & 15) * 4;
            Ks[rr][cc+0] = kv[i].x; Ks[rr][cc+1] = kv[i].y; Ks[rr][cc+2] = kv[i].z; Ks[rr][cc+3] = kv[i].w;
            Vs[rr][cc+0] = vv[i].x; Vs[rr][cc+1] = vv[i].y; Vs[rr][cc+2] = vv[i].z; Vs[rr][cc+3] = vv[i].w;
        }
        __syncthreads();

        // ---- scores: 16 per thread ----
        float sc[16];
        #pragma unroll
        for (int j = 0; j < 16; j++) sc[j] = 0.f;
        #pragma unroll 4
        for (int k4 = 0; k4 < 16; k4++) {
            float4 qv = *(const float4*)&Qs[r][k4 * 4];
            #pragma unroll
            for (int j = 0; j < 16; j++) {
                float4 kk2 = *(const float4*)&Ks[c0 + j][k4 * 4];
                sc[j] += qv.x*kk2.x + qv.y*kk2.y + qv.z*kk2.z + qv.w*kk2.w;
            }
        }
        const bool diag = (kt == qtile);
        #pragma unroll
        for (int j = 0; j < 16; j++) {
            sc[j] *= 0.125f;   // 1/sqrt(64)
            if (diag && (k0 + c0 + j) > (q0 + r)) sc[j] = -INFINITY;
        }

        // ---- row max (online softmax) ----
        float lm = sc[0];
        #pragma unroll
        for (int j = 1; j < 16; j++) lm = fmaxf(lm, sc[j]);
        red[r][t & 3] = lm;
        __syncthreads();
        if (t < 64) {
            float mt = fmaxf(fmaxf(red[t][0], red[t][1]), fmaxf(red[t][2], red[t][3]));
            float mo = m_s[t];
            float mn = fmaxf(mo, mt);
            a_s[t] = __expf(mo - mn);
            m_s[t] = mn;
        }
        __syncthreads();
        const float mn = m_s[r], alpha = a_s[r];
        float ps = 0.f;
        #pragma unroll
        for (int j = 0; j < 16; j++) {
            float p = __expf(sc[j] - mn);
            Ps[r][c0 + j] = p;
            ps += p;
        }
        #pragma unroll
        for (int i = 0; i < 16; i++) o[i] *= alpha;
        red[r][t & 3] = ps;
        __syncthreads();
        if (t < 64)
            l_s[t] = l_s[t] * a_s[t] + (red[t][0] + red[t][1] + red[t][2] + red[t][3]);

        // ---- O += P @ V ----
        #pragma unroll 4
        for (int j = 0; j < 64; j++) {
            const float pv = Ps[r][j];
            const float* vr = &Vs[j][c0];
            float4 v0 = *(const float4*)(vr);
            float4 v1 = *(const float4*)(vr + 4);
            float4 v2 = *(const float4*)(vr + 8);
            float4 v3 = *(const float4*)(vr + 12);
            o[0]  += pv * v0.x; o[1]  += pv * v0.y; o[2]  += pv * v0.z; o[3]  += pv * v0.w;
            o[4]  += pv * v1.x; o[5]  += pv * v1.y; o[6]  += pv * v1.z; o[7]  += pv * v1.w;
            o[8]  += pv * v2.x; o[9]  += pv * v2.y; o[10] += pv * v2.z; o[11] += pv * v2.w;
            o[12] += pv * v3.x; o[13] += pv * v3.y; o[14] += pv * v3.z; o[15] += pv * v3.w;
        }
    }
    __syncthreads();
    const float inv = 1.0f / l_s[r];
    const int b = bh >> 4, h = bh & (H_ - 1);
    const int s = q0 + r;
    float* ob = out + ((size_t)b * S_ + s) * D_ + h * DH_ + c0;
    #pragma unroll
    for (int i = 0; i < 4; i++) {
        float4 rv;
        rv.x = o[i*4+0] * inv; rv.y = o[i*4+1] * inv;
        rv.z = o[i*4+2] * inv; rv.w = o[i*4+3] * inv;
        *(float4*)(ob + i * 4) = rv;
    }
}

// ---------------------------------------------------------------------------
// out_row = LayerNorm(A_row + R_row) * g + b     (D = 1024, one block/row)
// ---------------------------------------------------------------------------
__global__ __launch_bounds__(256)
void add_ln_kernel(const float* __restrict__ A, const float* __restrict__ R,
                   const float* __restrict__ g, const float* __restrict__ bia,
                   float* __restrict__ out)
{
    const int row = blockIdx.x;
    const int t   = threadIdx.x;
    const float4 av = ((const float4*)(A + (size_t)row * D_))[t];
    const float4 rv = ((const float4*)(R + (size_t)row * D_))[t];
    float4 s;
    s.x = av.x + rv.x; s.y = av.y + rv.y; s.z = av.z + rv.z; s.w = av.w + rv.w;

    float sum = s.x + s.y + s.z + s.w;
    float sq  = s.x*s.x + s.y*s.y + s.z*s.z + s.w*s.w;
    #pragma unroll
    for (int off = 32; off > 0; off >>= 1) {
        sum += __shfl_down(sum, off);
        sq  += __shfl_down(sq,  off);
    }
    __shared__ float wsum[4], wsq[4], stat[2];
    const int wid = t >> 6, lane = t & 63;
    if (lane == 0) { wsum[wid] = sum; wsq[wid] = sq; }
    __syncthreads();
    if (t == 0) {
        float S = wsum[0] + wsum[1] + wsum[2] + wsum[3];
        float Q = wsq[0]  + wsq[1]  + wsq[2]  + wsq[3];
        float mean = S * (1.0f / D_);
        float var  = Q * (1.0f / D_) - mean * mean;
        stat[0] = mean;
        stat[1] = rsqrtf(var + 1e-5f);
    }
    __syncthreads();
    const float mean = stat[0], inv = stat[1];
    const float4 gv = ((const float4*)g)[t];
    const float4 bv = ((const float4*)bia)[t];
    float4 o;
    o.x = (s.x - mean) * inv * gv.x + bv.x;
    o.y = (s.y - mean) * inv * gv.y + bv.y;
    o.z = (s.z - mean) * inv * gv.z + bv.z;
    o.w = (s.w - mean) * inv * gv.w + bv.w;
    ((float4*)(out + (size_t)row * D_))[t] = o;
}

// ---------------------------------------------------------------------------
extern "C" void kernel_launch(void* const* d_in, const int* in_sizes, int n_in,
                              void* d_out, int out_size, void* d_ws, size_t ws_size,
                              hipStream_t stream)
{
    const float* x      = (const float*)d_in[0];
    const float* wq_w   = (const float*)d_in[1];
    const float* wq_b   = (const float*)d_in[2];
    const float* wk_w   = (const float*)d_in[3];
    const float* wk_b   = (const float*)d_in[4];
    const float* wv_w   = (const float*)d_in[5];
    const float* wv_b   = (const float*)d_in[6];
    const float* ln1_g  = (const float*)d_in[7];
    const float* ln1_b  = (const float*)d_in[8];
    const float* lin1_w = (const float*)d_in[9];
    const float* lin1_b = (const float*)d_in[10];
    const float* ln2_g  = (const float*)d_in[11];
    const float* ln2_b  = (const float*)d_in[12];
    float* out = (float*)d_out;

    float* ws = (float*)d_ws;
    const size_t NQKV = (size_t)B_ * H_ * S_ * DH_;   // 8,388,608 floats
    float* q = ws;
    float* k = ws + NQKV;
    float* v = ws + 2 * NQKV;
    // reuse after attention:
    float* h = q;            // post-LN1 activations
    float* y = k;            // lin1 output
    float* attn = out;       // stage attention output in d_out (overwritten later)

    dim3 gblk(256), ggrid(M_ / 64, D_ / 64);
    gemm_xwt<<<ggrid, gblk, 0, stream>>>(x, wq_w, wq_b, q, M_, D_, D_, 1);
    gemm_xwt<<<ggrid, gblk, 0, stream>>>(x, wk_w, wk_b, k, M_, D_, D_, 1);
    gemm_xwt<<<ggrid, gblk, 0, stream>>>(x, wv_w, wv_b, v, M_, D_, D_, 1);

    attn_kernel<<<dim3(S_ / 64, B_ * H_), 256, 0, stream>>>(q, k, v, attn);

    add_ln_kernel<<<M_, 256, 0, stream>>>(x, attn, ln1_g, ln1_b, h);

    gemm_xwt<<<ggrid, gblk, 0, stream>>>(h, lin1_w, lin1_b, y, M_, D_, D_, 0);

    add_ln_kernel<<<M_, 256, 0, stream>>>(h, y, ln2_g, ln2_b, out);
}

// Round 2
// 468.782 us; speedup vs baseline: 8.7223x; 8.7223x over previous
//
#include <hip/hip_runtime.h>
#include <math.h>

#define B_  4
#define S_  2048
#define D_  1024
#define H_  16
#define DH_ 64
#define M_  (B_*S_)

typedef unsigned short ushort_t;
typedef __attribute__((ext_vector_type(8))) __bf16 bf16x8;
typedef __attribute__((ext_vector_type(4))) float f32x4;
typedef __attribute__((ext_vector_type(8))) unsigned short us8;
typedef __attribute__((ext_vector_type(4))) unsigned short us4;

__device__ __forceinline__ ushort_t f2bf(float f) {
    unsigned int u = __float_as_uint(f);
    u = (u + 0x7fffu + ((u >> 16) & 1u)) >> 16;   // RNE
    return (ushort_t)u;
}

// async global->LDS, 16B per lane, wave-uniform LDS base (HW: base + lane*16)
#define GLD16(gp, lp) __builtin_amdgcn_global_load_lds( \
    (const __attribute__((address_space(1))) void*)(gp), \
    (__attribute__((address_space(3))) void*)(lp), 16, 0, 0)

#define WAIT_VM0()   __builtin_amdgcn_s_waitcnt(0x0F70)  // vmcnt(0) only
#define WAIT_LGKM0() __builtin_amdgcn_s_waitcnt(0xC07F)  // lgkmcnt(0) only

// ---------------------------------------------------------------------------
// fp32 -> bf16 converters
// ---------------------------------------------------------------------------
__global__ __launch_bounds__(256)
void cvt_kernel(const float* __restrict__ src, ushort_t* __restrict__ dst, int n)
{
    int i = (blockIdx.x * 256 + threadIdx.x) * 8;
    if (i >= n) return;
    float4 a = *(const float4*)(src + i);
    float4 b = *(const float4*)(src + i + 4);
    us8 r;
    r[0] = f2bf(a.x); r[1] = f2bf(a.y); r[2] = f2bf(a.z); r[3] = f2bf(a.w);
    r[4] = f2bf(b.x); r[5] = f2bf(b.y); r[6] = f2bf(b.z); r[7] = f2bf(b.w);
    *(us8*)(dst + i) = r;
}

__global__ __launch_bounds__(256)
void cvt_w4(const float* __restrict__ w0, const float* __restrict__ w1,
            const float* __restrict__ w2, const float* __restrict__ w3,
            ushort_t* __restrict__ dst)
{
    const int ten = blockIdx.y;
    const float* s = (ten == 0) ? w0 : (ten == 1) ? w1 : (ten == 2) ? w2 : w3;
    ushort_t* d = dst + (size_t)ten * (D_ * D_);
    int i = (blockIdx.x * 256 + threadIdx.x) * 8;
    float4 a = *(const float4*)(s + i);
    float4 b = *(const float4*)(s + i + 4);
    us8 r;
    r[0] = f2bf(a.x); r[1] = f2bf(a.y); r[2] = f2bf(a.z); r[3] = f2bf(a.w);
    r[4] = f2bf(b.x); r[5] = f2bf(b.y); r[6] = f2bf(b.z); r[7] = f2bf(b.w);
    *(us8*)(d + i) = r;
}

// ---------------------------------------------------------------------------
// MFMA GEMM: Y = A @ Bw^T + bias.  A:[M,K] bf16, Bw:[N,K] bf16 (torch weight).
// 128x128 tile, BK=32, 256 thr = 4 waves (2x2), 4x4 16x16x32 MFMAs per wave.
// mode 0: N=3072 fused QKV -> scatter Q(bf16,*0.125)/K(bf16)/V^T(bf16)
// mode 1: N=1024 -> fp32 Yf[m*1024+n]
// ---------------------------------------------------------------------------
__global__ __launch_bounds__(256)
void gemm_mfma(const ushort_t* __restrict__ A, const ushort_t* __restrict__ Bw,
               const float* __restrict__ bias0, const float* __restrict__ bias1,
               const float* __restrict__ bias2,
               float* __restrict__ Yf, ushort_t* __restrict__ Qo,
               ushort_t* __restrict__ Ko, ushort_t* __restrict__ Vo,
               int K, int mode)
{
    __shared__ __align__(16) ushort_t As[128 * 32];
    __shared__ __align__(16) ushort_t Bs[128 * 32];
    const int t = threadIdx.x;
    const int lane = t & 63, wave = t >> 6;
    const int wm = wave >> 1, wn = wave & 1;
    const int m0 = blockIdx.x * 128, n0 = blockIdx.y * 128;
    const int quad = lane >> 4, l15 = lane & 15;

    // staging geometry: 8 chunks of 1KB per tile; wave w stages chunks 2w,2w+1
    const int ch0 = wave * 2, ch1 = wave * 2 + 1;
    const int srow = lane >> 2;          // 0..15
    const int scol = (lane & 3) * 8;     // 0,8,16,24
    const ushort_t* Ap0 = A  + (size_t)(m0 + ch0 * 16 + srow) * K + scol;
    const ushort_t* Ap1 = A  + (size_t)(m0 + ch1 * 16 + srow) * K + scol;
    const ushort_t* Bp0 = Bw + (size_t)(n0 + ch0 * 16 + srow) * K + scol;
    const ushort_t* Bp1 = Bw + (size_t)(n0 + ch1 * 16 + srow) * K + scol;
    ushort_t* lA0 = As + ch0 * 512;
    ushort_t* lA1 = As + ch1 * 512;
    ushort_t* lB0 = Bs + ch0 * 512;
    ushort_t* lB1 = Bs + ch1 * 512;

    f32x4 acc[4][4] = {};

    for (int k0 = 0; k0 < K; k0 += 32) {
        GLD16(Ap0 + k0, lA0);
        GLD16(Ap1 + k0, lA1);
        GLD16(Bp0 + k0, lB0);
        GLD16(Bp1 + k0, lB1);
        WAIT_VM0();
        __syncthreads();

        bf16x8 af[4], bfr[4];
        #pragma unroll
        for (int i = 0; i < 4; i++)
            af[i] = *(const bf16x8*)(As + (64 * wm + 16 * i + l15) * 32 + quad * 8);
        #pragma unroll
        for (int j = 0; j < 4; j++)
            bfr[j] = *(const bf16x8*)(Bs + (64 * wn + 16 * j + l15) * 32 + quad * 8);
        #pragma unroll
        for (int i = 0; i < 4; i++)
            #pragma unroll
            for (int j = 0; j < 4; j++)
                acc[i][j] = __builtin_amdgcn_mfma_f32_16x16x32_bf16(af[i], bfr[j], acc[i][j], 0, 0, 0);
        __syncthreads();
    }

    // epilogue — C/D layout: row = quad*4+r, col = l15 (verified m89/m91)
    #pragma unroll
    for (int j = 0; j < 4; j++) {
        const int n = n0 + 64 * wn + 16 * j + l15;
        if (mode == 1) {
            const float bv = bias0[n];
            #pragma unroll
            for (int i = 0; i < 4; i++) {
                const int mrow = m0 + 64 * wm + 16 * i + quad * 4;
                float* yp = Yf + (size_t)mrow * D_ + n;
                #pragma unroll
                for (int r = 0; r < 4; r++)
                    yp[(size_t)r * D_] = acc[i][j][r] + bv;
            }
        } else {
            const int sel = n >> 10, nn = n & 1023;
            const int hh = nn >> 6, dd = nn & 63;
            const float bv = (sel == 0 ? bias0 : (sel == 1 ? bias1 : bias2))[nn];
            const float scl = (sel == 0) ? 0.125f : 1.0f;
            #pragma unroll
            for (int i = 0; i < 4; i++) {
                const int mrow = m0 + 64 * wm + 16 * i + quad * 4;
                const int b = mrow >> 11;
                const int ss = mrow & (S_ - 1);
                #pragma unroll
                for (int r = 0; r < 4; r++) {
                    const float v = (acc[i][j][r] + bv) * scl;
                    const ushort_t bvv = f2bf(v);
                    if (sel == 0)
                        Qo[(((size_t)b * H_ + hh) * S_ + ss + r) * DH_ + dd] = bvv;
                    else if (sel == 1)
                        Ko[(((size_t)b * H_ + hh) * S_ + ss + r) * DH_ + dd] = bvv;
                    else
                        Vo[(((size_t)b * H_ + hh) * DH_ + dd) * S_ + ss + r] = bvv;
                }
            }
        }
    }
}

// ---------------------------------------------------------------------------
// MFMA flash attention (causal).  Qb/Kb: [B,H,S,64] bf16 (Q pre-scaled 1/8),
// Vt: [B,H,64,S] bf16.  out: [B,S,D] fp32.
// Block: 256 thr = 4 waves; q-tile 64 (wave w owns rows 16w..16w+15).
// K/V tiles 64x64 staged via global_load_lds with XOR-8 swizzle.
// ---------------------------------------------------------------------------
__global__ __launch_bounds__(256)
void attn_mfma(const ushort_t* __restrict__ Qb, const ushort_t* __restrict__ Kb,
               const ushort_t* __restrict__ Vt, float* __restrict__ out)
{
    __shared__ __align__(16) ushort_t Ks[64 * 64];
    __shared__ __align__(16) ushort_t Vs[64 * 64];
    __shared__ __align__(16) ushort_t Ps[4 * 16 * 72];
    const int t = threadIdx.x, lane = t & 63, w = t >> 6;
    const int qtile = (int)gridDim.x - 1 - (int)blockIdx.x;   // big tiles first
    const int bh = blockIdx.y;
    const int q0 = qtile * 64;
    const int quad = lane >> 4, l15 = lane & 15;

    // Q fragments stay in registers (A-layout: m=l15, k=quad*8+j)
    const int qr = q0 + 16 * w + l15;
    const ushort_t* qp = Qb + ((size_t)bh * S_ + qr) * DH_;
    const bf16x8 fq0 = *(const bf16x8*)(qp + quad * 8);
    const bf16x8 fq1 = *(const bf16x8*)(qp + 32 + quad * 8);

    f32x4 o[4] = {};
    float m_i[4], l_i[4];
    #pragma unroll
    for (int r = 0; r < 4; r++) { m_i[r] = -INFINITY; l_i[r] = 0.f; }

    // staging: 8 K-chunks + 8 V-chunks of 1KB; wave w: chunks 2w,2w+1 of each
    const int c0 = 2 * w, c1 = 2 * w + 1;
    const int srow = lane >> 3;                   // row-within-chunk 0..7
    const int scol = 8 * ((lane & 7) ^ srow);     // swizzled source column
    const ushort_t* Kg0 = Kb + ((size_t)bh * S_ + c0 * 8 + srow) * DH_ + scol;
    const ushort_t* Kg1 = Kb + ((size_t)bh * S_ + c1 * 8 + srow) * DH_ + scol;
    const ushort_t* Vg0 = Vt + ((size_t)bh * DH_ + c0 * 8 + srow) * S_ + scol;
    const ushort_t* Vg1 = Vt + ((size_t)bh * DH_ + c1 * 8 + srow) * S_ + scol;
    ushort_t* lK0 = Ks + c0 * 512;
    ushort_t* lK1 = Ks + c1 * 512;
    ushort_t* lV0 = Vs + c0 * 512;
    ushort_t* lV1 = Vs + c1 * 512;
    ushort_t* pw = Ps + w * 1152;                 // [16][72] per wave

    for (int kt = 0; kt <= qtile; kt++) {
        const int k0 = kt * 64;
        GLD16(Kg0 + (size_t)k0 * DH_, lK0);
        GLD16(Kg1 + (size_t)k0 * DH_, lK1);
        GLD16(Vg0 + k0, lV0);
        GLD16(Vg1 + k0, lV1);
        WAIT_VM0();
        __syncthreads();

        // ---- scores S = Q K^T (already scaled via Q) ----
        f32x4 sc[4] = {};
        #pragma unroll
        for (int ct = 0; ct < 4; ct++) {
            const int n = ct * 16 + l15;          // key within tile
            const int sw = 8 * (n & 7);
            bf16x8 b0 = *(const bf16x8*)(Ks + n * 64 + ((quad * 8) ^ sw));
            bf16x8 b1 = *(const bf16x8*)(Ks + n * 64 + ((32 + quad * 8) ^ sw));
            sc[ct] = __builtin_amdgcn_mfma_f32_16x16x32_bf16(fq0, b0, sc[ct], 0, 0, 0);
            sc[ct] = __builtin_amdgcn_mfma_f32_16x16x32_bf16(fq1, b1, sc[ct], 0, 0, 0);
        }

        if (kt == qtile) {                        // diagonal tile: causal mask
            const int qg = q0 + 16 * w + quad * 4;
            #pragma unroll
            for (int ct = 0; ct < 4; ct++) {
                const int key = k0 + ct * 16 + l15;
                #pragma unroll
                for (int r = 0; r < 4; r++)
                    if (key > qg + r) sc[ct][r] = -INFINITY;
            }
        }

        // ---- online softmax (rows live across 16-lane groups) ----
        float vr[4];
        #pragma unroll
        for (int r = 0; r < 4; r++)
            vr[r] = fmaxf(fmaxf(sc[0][r], sc[1][r]), fmaxf(sc[2][r], sc[3][r]));
        #pragma unroll
        for (int off = 1; off < 16; off <<= 1)
            #pragma unroll
            for (int r = 0; r < 4; r++)
                vr[r] = fmaxf(vr[r], __shfl_xor(vr[r], off));

        float alpha[4], rs[4];
        #pragma unroll
        for (int r = 0; r < 4; r++) {
            const float mn = fmaxf(m_i[r], vr[r]);
            alpha[r] = __expf(m_i[r] - mn);
            m_i[r] = mn;
            rs[r] = 0.f;
        }
        #pragma unroll
        for (int ct = 0; ct < 4; ct++)
            #pragma unroll
            for (int r = 0; r < 4; r++) {
                const float p = __expf(sc[ct][r] - m_i[r]);
                rs[r] += p;
                pw[(quad * 4 + r) * 72 + ct * 16 + l15] = f2bf(p);
            }
        #pragma unroll
        for (int off = 1; off < 16; off <<= 1)
            #pragma unroll
            for (int r = 0; r < 4; r++)
                rs[r] += __shfl_xor(rs[r], off);
        #pragma unroll
        for (int r = 0; r < 4; r++)
            l_i[r] = l_i[r] * alpha[r] + rs[r];
        #pragma unroll
        for (int jt = 0; jt < 4; jt++)
            #pragma unroll
            for (int r = 0; r < 4; r++)
                o[jt][r] *= alpha[r];

        // ---- O += P V  (P via per-wave LDS round-trip to A-layout) ----
        WAIT_LGKM0();
        asm volatile("" ::: "memory");
        const bf16x8 pf0 = *(const bf16x8*)(pw + l15 * 72 + quad * 8);
        const bf16x8 pf1 = *(const bf16x8*)(pw + l15 * 72 + 32 + quad * 8);
        #pragma unroll
        for (int jt = 0; jt < 4; jt++) {
            const int n = jt * 16 + l15;          // dh within head
            const int sw = 8 * (n & 7);
            bf16x8 v0 = *(const bf16x8*)(Vs + n * 64 + ((quad * 8) ^ sw));
            bf16x8 v1 = *(const bf16x8*)(Vs + n * 64 + ((32 + quad * 8) ^ sw));
            o[jt] = __builtin_amdgcn_mfma_f32_16x16x32_bf16(pf0, v0, o[jt], 0, 0, 0);
            o[jt] = __builtin_amdgcn_mfma_f32_16x16x32_bf16(pf1, v1, o[jt], 0, 0, 0);
        }
        __syncthreads();
    }

    float inv[4];
    #pragma unroll
    for (int r = 0; r < 4; r++) inv[r] = 1.0f / l_i[r];
    const int b = bh >> 4, h = bh & (H_ - 1);
    #pragma unroll
    for (int jt = 0; jt < 4; jt++)
        #pragma unroll
        for (int r = 0; r < 4; r++) {
            const int sg = q0 + 16 * w + quad * 4 + r;
            out[((size_t)(b * S_ + sg)) * D_ + h * DH_ + jt * 16 + l15] = o[jt][r] * inv[r];
        }
}

// ---------------------------------------------------------------------------
// out = LayerNorm(A + R) * g + b ; optional bf16 copy of out
// ---------------------------------------------------------------------------
__global__ __launch_bounds__(256)
void add_ln_kernel(const float* __restrict__ A, const float* __restrict__ R,
                   const float* __restrict__ g, const float* __restrict__ bia,
                   float* __restrict__ out, ushort_t* __restrict__ out_bf)
{
    const int row = blockIdx.x;
    const int t   = threadIdx.x;
    const float4 av = ((const float4*)(A + (size_t)row * D_))[t];
    const float4 rv = ((const float4*)(R + (size_t)row * D_))[t];
    float4 s;
    s.x = av.x + rv.x; s.y = av.y + rv.y; s.z = av.z + rv.z; s.w = av.w + rv.w;

    float sum = s.x + s.y + s.z + s.w;
    float sq  = s.x*s.x + s.y*s.y + s.z*s.z + s.w*s.w;
    #pragma unroll
    for (int off = 32; off > 0; off >>= 1) {
        sum += __shfl_down(sum, off);
        sq  += __shfl_down(sq,  off);
    }
    __shared__ float wsum[4], wsq[4], stat[2];
    const int wid = t >> 6, lane = t & 63;
    if (lane == 0) { wsum[wid] = sum; wsq[wid] = sq; }
    __syncthreads();
    if (t == 0) {
        float S = wsum[0] + wsum[1] + wsum[2] + wsum[3];
        float Q = wsq[0]  + wsq[1]  + wsq[2]  + wsq[3];
        float mean = S * (1.0f / D_);
        float var  = Q * (1.0f / D_) - mean * mean;
        stat[0] = mean;
        stat[1] = rsqrtf(var + 1e-5f);
    }
    __syncthreads();
    const float mean = stat[0], inv = stat[1];
    const float4 gv = ((const float4*)g)[t];
    const float4 bv = ((const float4*)bia)[t];
    float4 o;
    o.x = (s.x - mean) * inv * gv.x + bv.x;
    o.y = (s.y - mean) * inv * gv.y + bv.y;
    o.z = (s.z - mean) * inv * gv.z + bv.z;
    o.w = (s.w - mean) * inv * gv.w + bv.w;
    ((float4*)(out + (size_t)row * D_))[t] = o;
    if (out_bf) {
        us4 ob;
        ob[0] = f2bf(o.x); ob[1] = f2bf(o.y); ob[2] = f2bf(o.z); ob[3] = f2bf(o.w);
        *(us4*)(out_bf + (size_t)row * D_ + t * 4) = ob;
    }
}

// ---------------------------------------------------------------------------
extern "C" void kernel_launch(void* const* d_in, const int* in_sizes, int n_in,
                              void* d_out, int out_size, void* d_ws, size_t ws_size,
                              hipStream_t stream)
{
    const float* x      = (const float*)d_in[0];
    const float* wq_w   = (const float*)d_in[1];
    const float* wq_b   = (const float*)d_in[2];
    const float* wk_w   = (const float*)d_in[3];
    const float* wk_b   = (const float*)d_in[4];
    const float* wv_w   = (const float*)d_in[5];
    const float* wv_b   = (const float*)d_in[6];
    const float* ln1_g  = (const float*)d_in[7];
    const float* ln1_b  = (const float*)d_in[8];
    const float* lin1_w = (const float*)d_in[9];
    const float* lin1_b = (const float*)d_in[10];
    const float* ln2_g  = (const float*)d_in[11];
    const float* ln2_b  = (const float*)d_in[12];
    float* out = (float*)d_out;

    char* base = (char*)d_ws;
    // ws layout (bytes):
    //   x_bf  @ 0         : 16,777,216  (8.4M bf16)
    //   w_bf  @ 16777216  : 8,388,608   ([wq|wk|wv|lin1] each 1M bf16)
    //   Qbf   @ 25165824  : 16,777,216
    //   Kbf   @ 41943040  : 16,777,216
    //   Vt    @ 58720256  : 16,777,216  (total 75.5 MB)
    //   h     @ 25165824  (fp32, aliases Qbf+Kbf — used only after attention)
    //   h_bf  @ 58720256  (bf16, aliases Vt    — used only after attention)
    ushort_t* x_bf = (ushort_t*)(base);
    ushort_t* w_bf = (ushort_t*)(base + 16777216);
    ushort_t* Qbf  = (ushort_t*)(base + 25165824);
    ushort_t* Kbf  = (ushort_t*)(base + 41943040);
    ushort_t* Vtp  = (ushort_t*)(base + 58720256);
    float*    h    = (float*)   (base + 25165824);
    ushort_t* h_bf = (ushort_t*)(base + 58720256);

    cvt_kernel<<<dim3((M_ * D_) / 2048), 256, 0, stream>>>(x, x_bf, M_ * D_);
    cvt_w4<<<dim3((D_ * D_) / 2048, 4), 256, 0, stream>>>(wq_w, wk_w, wv_w, lin1_w, w_bf);

    // fused QKV projection (N = 3072)
    gemm_mfma<<<dim3(M_ / 128, 3072 / 128), 256, 0, stream>>>(
        x_bf, w_bf, wq_b, wk_b, wv_b, nullptr, Qbf, Kbf, Vtp, D_, 0);

    attn_mfma<<<dim3(S_ / 64, B_ * H_), 256, 0, stream>>>(Qbf, Kbf, Vtp, out);

    add_ln_kernel<<<M_, 256, 0, stream>>>(x, out, ln1_g, ln1_b, h, h_bf);

    // lin1 (N = 1024) -> fp32 into d_out (attn output already consumed)
    gemm_mfma<<<dim3(M_ / 128, D_ / 128), 256, 0, stream>>>(
        h_bf, w_bf + 3 * D_ * D_, lin1_b, nullptr, nullptr, out, nullptr, nullptr, nullptr, D_, 1);

    add_ln_kernel<<<M_, 256, 0, stream>>>(h, out, ln2_g, ln2_b, out, nullptr);
}